// Round 16
// baseline (165.353 us; speedup 1.0000x reference)
//
#include <hip/hip_runtime.h>
#include <math.h>

// Retinex MSR via GEMM: blur_s = G_s * X * G_s  (G_s symmetric Toeplitz blur).
// xconv: X -> f16. gemm1: Ys^T[a][b] = sum_k G_s[a][k] X[b][k].
// gemm2: out = sum_s log(G_s*Y_s + 1)/3, fused min/max reduction.
// GEMM core: 128x128 tile, BK=64 (2 K-slots of 32), TWO LDS buffers, ONE
// __syncthreads per K-step (r6-proven race-free ordering), pointer staging,
// r15 XCD-aware block swizzle. Steps per block halve vs BK=32.

#define NSL 48

// d_ws layout:
#define W0_OFF 0      // sigma 15:  16 zero | 91 w | zeros   (alloc 512 floats)
#define W1_OFF 512    // sigma 80:  16 zero | 481 w | zeros  (alloc 768)
#define W2_OFF 1280   // sigma 250: 16 zero | 1501 w | zeros (alloc 1536)
#define MM_OFF 2816   // 6 uints: min[3], max[3]
#define G16_BYTE_OFF 16384     // 3 * 512*512 f16   (1.5 MiB)
#define X16_BYTE_OFF 1589248   // 48 * 512*512 f16  (24 MiB)
#define T16_BYTE_OFF 26755072  // 3 * 48 * 512*512 f16 (72 MiB)

typedef _Float16 half8 __attribute__((ext_vector_type(8)));
typedef float f32x4 __attribute__((ext_vector_type(4)));

__device__ __forceinline__ void gload16(const void* g, void* l) {
  __builtin_amdgcn_global_load_lds(
      (const __attribute__((address_space(1))) void*)g,
      (__attribute__((address_space(3))) void*)l, 16, 0, 0);
}

// ---------------- weights ----------------
__global__ void wkern(float* __restrict__ ws) {
  __shared__ float red[256];
  const int s = blockIdx.x;
  const int Ks[3] = {91, 481, 1501};
  const float sg[3] = {15.f, 80.f, 250.f};
  const int off[3] = {W0_OFF, W1_OFF, W2_OFF};
  const int alloc[3] = {512, 768, 1536};
  const int K = Ks[s], A = alloc[s];
  float* wb = ws + off[s];
  const int t = threadIdx.x;
  for (int i = t; i < A; i += 256) wb[i] = 0.f;
  __syncthreads();
  const float inv2s2 = 1.f / (2.f * sg[s] * sg[s]);
  float part = 0.f;
  for (int i = t; i < K; i += 256) {
    const float d = (float)(i - K / 2);
    const float e = __expf(-d * d * inv2s2);
    wb[16 + i] = e;
    part += e;
  }
  red[t] = part;
  __syncthreads();
  for (int st = 128; st > 0; st >>= 1) {
    if (t < st) red[t] += red[t + st];
    __syncthreads();
  }
  const float inv = 1.f / red[0];
  for (int i = t; i < K; i += 256) wb[16 + i] *= inv;
}

__global__ void mm_init(unsigned* __restrict__ mm) {
  const int t = threadIdx.x;
  if (t < 3) mm[t] = 0xFFFFFFFFu;
  else if (t < 6) mm[t] = 0u;
}

// ---------------- build G matrices (fp16) ----------------
__global__ void gkern(const float* __restrict__ ws, _Float16* __restrict__ gb) {
  const int y = blockIdx.x;
  const int s = blockIdx.y;
  const int Rs[3] = {45, 240, 750};
  const int off[3] = {W0_OFF, W1_OFF, W2_OFF};
  const float* w = ws + off[s] + 16;
  _Float16* g = gb + ((size_t)s << 18) + ((size_t)y << 9);
  const int R = Rs[s], K = 2 * R + 1;
  for (int x = threadIdx.x; x < 512; x += 256) {
    const int i = x - y + R;
    const float v = (i >= 0 && i < K) ? w[i] : 0.f;
    g[x] = (_Float16)v;
  }
}

// ---------------- X fp32 -> fp16 ----------------
__global__ __launch_bounds__(256) void xconv(const float* __restrict__ X,
                                             _Float16* __restrict__ X16) {
  const size_t i = ((size_t)blockIdx.x * 256 + threadIdx.x) << 3;
  const float4 v0 = *reinterpret_cast<const float4*>(X + i);
  const float4 v1 = *reinterpret_cast<const float4*>(X + i + 4);
  half8 h;
  h[0] = (_Float16)v0.x; h[1] = (_Float16)v0.y;
  h[2] = (_Float16)v0.z; h[3] = (_Float16)v0.w;
  h[4] = (_Float16)v1.x; h[5] = (_Float16)v1.y;
  h[6] = (_Float16)v1.z; h[7] = (_Float16)v1.w;
  *reinterpret_cast<half8*>(X16 + i) = h;
}

// stage one 128x64 A-tile + 128x64 B-tile (8 gload16/thread) via 8 pointers;
// advance by 64 elems after. Chunk c covers rows c*32..c*32+31 (granule idx =
// c*256 + t -> row = idx>>3, col-granule = idx&7).
#define STAGE8(buf)                                    \
  do {                                                 \
    gload16(pA0, &As[buf][t << 3]);                    \
    gload16(pA1, &As[buf][(256 + t) << 3]);            \
    gload16(pA2, &As[buf][(512 + t) << 3]);            \
    gload16(pA3, &As[buf][(768 + t) << 3]);            \
    gload16(pB0, &Bs[buf][t << 3]);                    \
    gload16(pB1, &Bs[buf][(256 + t) << 3]);            \
    gload16(pB2, &Bs[buf][(512 + t) << 3]);            \
    gload16(pB3, &Bs[buf][(768 + t) << 3]);            \
    pA0 += 64; pA1 += 64; pA2 += 64; pA3 += 64;        \
    pB0 += 64; pB1 += 64; pB2 += 64; pB3 += 64;        \
  } while (0)

// per K-step: 2 K-slots of 32; per slot 4 A-frags + 4 B-frags + 16 MFMA.
// LDS row stride = 64 elems; slot ks offset = ks*32 + lg*8.
#define FRAGS_AND_MFMA(buf)                                                         \
  do {                                                                              \
    _Pragma("unroll") for (int ks = 0; ks < 2; ++ks) {                              \
      half8 af[4], bf[4];                                                           \
      _Pragma("unroll") for (int f = 0; f < 4; ++f) {                               \
        af[f] = *reinterpret_cast<const half8*>(                                    \
            &As[buf][(((wr << 6) + (f << 4) + lr) << 6) + (ks << 5) + (lg << 3)]);  \
        bf[f] = *reinterpret_cast<const half8*>(                                    \
            &Bs[buf][(((wc << 6) + (f << 4) + lr) << 6) + (ks << 5) + (lg << 3)]);  \
      }                                                                             \
      _Pragma("unroll") for (int fm = 0; fm < 4; ++fm)                              \
          _Pragma("unroll") for (int fn = 0; fn < 4; ++fn)                          \
          acc[fm][fn] = __builtin_amdgcn_mfma_f32_16x16x32_f16(af[fm], bf[fn],      \
                                                               acc[fm][fn], 0, 0, 0); \
    }                                                                               \
  } while (0)

// r6-proven loop at BK=64: prologue stage buf0; per iter: sync (drains prev
// stage loads + all reads), stage next into other buf, compute current.
// Overwrite safety: the buf being staged at iter m was computed at m-1 and all
// waves passed the iter-m sync after that compute; loads land before iter m+1's
// sync. Band is in 64-col tiles: always >= 1 tile, fully in [0,512).
#define K_PIPELINE_LOOP()                                                           \
  do {                                                                              \
    const int rA_ = t >> 3;                                                         \
    const int g8_ = (t & 7) << 3;                                                   \
    const _Float16* pA0 = Ap + ((size_t)(bm + rA_) << 9) + (klo << 6) + g8_;        \
    const _Float16* pA1 = pA0 + ((size_t)32 << 9);                                  \
    const _Float16* pA2 = pA0 + ((size_t)64 << 9);                                  \
    const _Float16* pA3 = pA0 + ((size_t)96 << 9);                                  \
    const _Float16* pB0 = Bp + ((size_t)(bn + rA_) << 9) + (klo << 6) + g8_;        \
    const _Float16* pB1 = pB0 + ((size_t)32 << 9);                                  \
    const _Float16* pB2 = pB0 + ((size_t)64 << 9);                                  \
    const _Float16* pB3 = pB0 + ((size_t)96 << 9);                                  \
    STAGE8(0);                                                                      \
    int cb = 0;                                                                     \
    for (int kt = klo; kt <= khi; ++kt) {                                           \
      __syncthreads();                                                              \
      if (kt < khi) STAGE8(cb ^ 1);                                                 \
      FRAGS_AND_MFMA(cb);                                                           \
      cb ^= 1;                                                                      \
    }                                                                               \
  } while (0)

// ---------------- stage 1: Ys^T = G_s * X^T (B = X rows) ----------------
// Grid (8, 288). r15 decode: blocks sharing an X row-panel (same bn,slice)
// have identical linear%8 -> same XCD.
__global__ __launch_bounds__(256) void gemm1_k(const _Float16* __restrict__ X16,
                                               const _Float16* __restrict__ G16,
                                               _Float16* __restrict__ T16) {
  __shared__ __align__(16) _Float16 As[2][128 * 64];
  __shared__ __align__(16) _Float16 Bs[2][128 * 64];
  const int t = threadIdx.x;
  const int lane = t & 63, wave = t >> 6;
  const int wr = wave >> 1, wc = wave & 1;
  const int lr = lane & 15, lg = lane >> 4;
  const int idx = blockIdx.x;             // 0..7
  const int idy = blockIdx.y;             // 0..287
  const int idx12 = idy % 12;             // bm + 4*s
  const int q = idx + ((idy / 12) << 3);  // 0..191 = bn + 4*slice
  const int bn = (q & 3) << 7;
  const int slice = q >> 2;
  const int bm = (idx12 & 3) << 7;
  const int s = idx12 >> 2;
  const int Rs[3] = {45, 240, 750};
  const int R = Rs[s];
  const _Float16* Ap = G16 + ((size_t)s << 18);      // A = G_s (bm rows, band clip)
  const _Float16* Bp = X16 + ((size_t)slice << 18);  // B = X rows
  _Float16* Tout = T16 + ((size_t)(s * NSL + slice) << 18);  // Tout[a][b] = Ys^T

  int klo = bm - R;
  klo = (klo > 0 ? klo : 0) >> 6;
  int khi = bm + 127 + R;
  if (khi > 511) khi = 511;
  khi >>= 6;

  f32x4 acc[4][4];
#pragma unroll
  for (int i = 0; i < 4; ++i)
#pragma unroll
    for (int j = 0; j < 4; ++j) acc[i][j] = (f32x4){0.f, 0.f, 0.f, 0.f};

  K_PIPELINE_LOOP();

  // D[a][b]: a = bm+wr*64+fm*16+lg*4+j, b = bn+wc*64+fn*16+lr. Row-major runs.
#pragma unroll
  for (int fm = 0; fm < 4; ++fm)
#pragma unroll
    for (int fn = 0; fn < 4; ++fn) {
      const int a0 = bm + (wr << 6) + (fm << 4) + (lg << 2);
      const int b0 = bn + (wc << 6) + (fn << 4) + lr;
#pragma unroll
      for (int j = 0; j < 4; ++j)
        Tout[((size_t)(a0 + j) << 9) + b0] = (_Float16)acc[fm][fn][j];
    }
}

// ---------------- stage 2 fused: out = sum_s log(G_s*Y_s + 1)/3, + min/max ----------------
// Grid (8, 96). r15 decode: 4 bm-blocks sharing T16 row-panels co-locate.
__global__ __launch_bounds__(256) void gemm2_k(const _Float16* __restrict__ G16,
                                               const _Float16* __restrict__ T16,
                                               float* __restrict__ out,
                                               unsigned* __restrict__ mm) {
  __shared__ __align__(16) _Float16 As[2][128 * 64];
  __shared__ __align__(16) _Float16 Bs[2][128 * 64];
  __shared__ float smn[4], smx[4];
  const int t = threadIdx.x;
  const int lane = t & 63, wave = t >> 6;
  const int wr = wave >> 1, wc = wave & 1;
  const int lr = lane & 15, lg = lane >> 4;
  const int idx = blockIdx.x;             // 0..7
  const int idy = blockIdx.y;             // 0..95
  const int bm = (idy & 3) << 7;
  const int q = idx + ((idy >> 2) << 3);  // 0..191 = bn + 4*slice
  const int bn = (q & 3) << 7;
  const int slice = q >> 2;
  const float w3 = 1.f / 3.f;
  const int Rs[3] = {45, 240, 750};

  f32x4 res[4][4];
#pragma unroll
  for (int i = 0; i < 4; ++i)
#pragma unroll
    for (int j = 0; j < 4; ++j) res[i][j] = (f32x4){0.f, 0.f, 0.f, 0.f};

#pragma unroll 1
  for (int s = 0; s < 3; ++s) {
    const int R = Rs[s];
    const _Float16* Ap = G16 + ((size_t)s << 18);
    const _Float16* Bp = T16 + ((size_t)(s * NSL + slice) << 18);
    int klo = bm - R;
    klo = (klo > 0 ? klo : 0) >> 6;
    int khi = bm + 127 + R;
    if (khi > 511) khi = 511;
    khi >>= 6;

    f32x4 acc[4][4];
#pragma unroll
    for (int i = 0; i < 4; ++i)
#pragma unroll
      for (int j = 0; j < 4; ++j) acc[i][j] = (f32x4){0.f, 0.f, 0.f, 0.f};

    __syncthreads();  // full drain: prev sigma's reads done before restaging buf0
    K_PIPELINE_LOOP();

#pragma unroll
    for (int fm = 0; fm < 4; ++fm)
#pragma unroll
      for (int fn = 0; fn < 4; ++fn)
#pragma unroll
        for (int j = 0; j < 4; ++j)
          res[fm][fn][j] += w3 * __logf(acc[fm][fn][j] + 1.f);
  }

  // write out + fused per-channel min/max
  float mn = 3.4e38f, mx = -3.4e38f;
#pragma unroll
  for (int fm = 0; fm < 4; ++fm)
#pragma unroll
    for (int fn = 0; fn < 4; ++fn) {
      const int rb = bm + (wr << 6) + (fm << 4) + (lg << 2);
      const int cg = bn + (wc << 6) + (fn << 4) + lr;
      float* op = out + ((size_t)slice << 18) + ((size_t)rb << 9) + cg;
#pragma unroll
      for (int j = 0; j < 4; ++j) {
        const float v = res[fm][fn][j];
        op[j << 9] = v;
        mn = fminf(mn, v);
        mx = fmaxf(mx, v);
      }
    }
#pragma unroll
  for (int off = 32; off > 0; off >>= 1) {
    mn = fminf(mn, __shfl_xor(mn, off));
    mx = fmaxf(mx, __shfl_xor(mx, off));
  }
  if (lane == 0) {
    smn[wave] = mn;
    smx[wave] = mx;
  }
  __syncthreads();
  if (t == 0) {
    mn = fminf(fminf(smn[0], smn[1]), fminf(smn[2], smn[3]));
    mx = fmaxf(fmaxf(smx[0], smx[1]), fmaxf(smx[2], smx[3]));
    const int ch = slice % 3;
    atomicMin(&mm[ch], __float_as_uint(mn));  // values >= 0
    atomicMax(&mm[3 + ch], __float_as_uint(mx));
  }
}

// ---------------- normalize ----------------
__global__ __launch_bounds__(256) void norm_k(float* __restrict__ r,
                                              const unsigned* __restrict__ mm) {
  const int b = blockIdx.x;
  const int slice = b >> 4;
  const int piece = b & 15;
  const int ch = slice % 3;
  const float mn = __uint_as_float(mm[ch]);
  const float mx = __uint_as_float(mm[3 + ch]);
  const float inv = 1.f / (mx - mn);
  float* p = r + ((size_t)slice << 18) + (piece << 14);
  const int t = threadIdx.x;
  for (int q = 0; q < 16; ++q) {
    float4 v = *reinterpret_cast<const float4*>(&p[(q * 256 + t) << 2]);
    v.x = (v.x - mn) * inv;
    v.y = (v.y - mn) * inv;
    v.z = (v.z - mn) * inv;
    v.w = (v.w - mn) * inv;
    *reinterpret_cast<float4*>(&p[(q * 256 + t) << 2]) = v;
  }
}

extern "C" void kernel_launch(void* const* d_in, const int* in_sizes, int n_in,
                              void* d_out, int out_size, void* d_ws, size_t ws_size,
                              hipStream_t stream) {
  const float* img = (const float*)d_in[0];
  float* out = (float*)d_out;
  float* wsf = (float*)d_ws;
  unsigned* mm = (unsigned*)(wsf + MM_OFF);
  _Float16* G16 = (_Float16*)((char*)d_ws + G16_BYTE_OFF);
  _Float16* X16 = (_Float16*)((char*)d_ws + X16_BYTE_OFF);
  _Float16* T16 = (_Float16*)((char*)d_ws + T16_BYTE_OFF);

  wkern<<<3, 256, 0, stream>>>(wsf);
  mm_init<<<1, 64, 0, stream>>>(mm);
  gkern<<<dim3(512, 3), 256, 0, stream>>>(wsf, G16);
  xconv<<<6144, 256, 0, stream>>>(img, X16);

  gemm1_k<<<dim3(8, 288), 256, 0, stream>>>(X16, G16, T16);
  gemm2_k<<<dim3(8, 96), 256, 0, stream>>>(G16, T16, out, mm);

  norm_k<<<768, 256, 0, stream>>>(out, mm);
}

// Round 17
// 147.645 us; speedup vs baseline: 1.1199x; 1.1199x over previous
//
#include <hip/hip_runtime.h>
#include <math.h>

// Retinex MSR via GEMM: blur_s = G_s * X * G_s  (G_s symmetric Toeplitz blur).
// xconv: X -> f16. gemm1: Ys^T[a][b] = sum_k G_s[a][k] X[b][k]  (BK=32,
// 3-buffer counted-vmcnt pipeline — r15 best form, ~54us).
// gemm2: out = sum_s log(G_s*Y_s + 1)/3 + fused min/max  (BK=64, 2-buffer
// single-sync loop + BOTH-SIDES granule XOR swizzle to kill the 128B-stride
// 16-way bank conflict; swizzle pattern verified end-to-end in r12).
// Both use r15 XCD-aware block decode. norm: min-max stretch.

#define NSL 48

// d_ws layout:
#define W0_OFF 0      // sigma 15:  16 zero | 91 w | zeros   (alloc 512 floats)
#define W1_OFF 512    // sigma 80:  16 zero | 481 w | zeros  (alloc 768)
#define W2_OFF 1280   // sigma 250: 16 zero | 1501 w | zeros (alloc 1536)
#define MM_OFF 2816   // 6 uints: min[3], max[3]
#define G16_BYTE_OFF 16384     // 3 * 512*512 f16   (1.5 MiB)
#define X16_BYTE_OFF 1589248   // 48 * 512*512 f16  (24 MiB)
#define T16_BYTE_OFF 26755072  // 3 * 48 * 512*512 f16 (72 MiB)

typedef _Float16 half8 __attribute__((ext_vector_type(8)));
typedef float f32x4 __attribute__((ext_vector_type(4)));

__device__ __forceinline__ void gload16(const void* g, void* l) {
  __builtin_amdgcn_global_load_lds(
      (const __attribute__((address_space(1))) void*)g,
      (__attribute__((address_space(3))) void*)l, 16, 0, 0);
}

#define WAITV4() asm volatile("s_waitcnt vmcnt(4)" ::: "memory")
#define WAITV0() asm volatile("s_waitcnt vmcnt(0)" ::: "memory")
#define SCHEDB() __builtin_amdgcn_sched_barrier(0)
#define BARRIER() __builtin_amdgcn_s_barrier()

// ---------------- weights ----------------
__global__ void wkern(float* __restrict__ ws) {
  __shared__ float red[256];
  const int s = blockIdx.x;
  const int Ks[3] = {91, 481, 1501};
  const float sg[3] = {15.f, 80.f, 250.f};
  const int off[3] = {W0_OFF, W1_OFF, W2_OFF};
  const int alloc[3] = {512, 768, 1536};
  const int K = Ks[s], A = alloc[s];
  float* wb = ws + off[s];
  const int t = threadIdx.x;
  for (int i = t; i < A; i += 256) wb[i] = 0.f;
  __syncthreads();
  const float inv2s2 = 1.f / (2.f * sg[s] * sg[s]);
  float part = 0.f;
  for (int i = t; i < K; i += 256) {
    const float d = (float)(i - K / 2);
    const float e = __expf(-d * d * inv2s2);
    wb[16 + i] = e;
    part += e;
  }
  red[t] = part;
  __syncthreads();
  for (int st = 128; st > 0; st >>= 1) {
    if (t < st) red[t] += red[t + st];
    __syncthreads();
  }
  const float inv = 1.f / red[0];
  for (int i = t; i < K; i += 256) wb[16 + i] *= inv;
}

__global__ void mm_init(unsigned* __restrict__ mm) {
  const int t = threadIdx.x;
  if (t < 3) mm[t] = 0xFFFFFFFFu;
  else if (t < 6) mm[t] = 0u;
}

// ---------------- build G matrices (fp16) ----------------
__global__ void gkern(const float* __restrict__ ws, _Float16* __restrict__ gb) {
  const int y = blockIdx.x;
  const int s = blockIdx.y;
  const int Rs[3] = {45, 240, 750};
  const int off[3] = {W0_OFF, W1_OFF, W2_OFF};
  const float* w = ws + off[s] + 16;
  _Float16* g = gb + ((size_t)s << 18) + ((size_t)y << 9);
  const int R = Rs[s], K = 2 * R + 1;
  for (int x = threadIdx.x; x < 512; x += 256) {
    const int i = x - y + R;
    const float v = (i >= 0 && i < K) ? w[i] : 0.f;
    g[x] = (_Float16)v;
  }
}

// ---------------- X fp32 -> fp16 ----------------
__global__ __launch_bounds__(256) void xconv(const float* __restrict__ X,
                                             _Float16* __restrict__ X16) {
  const size_t i = ((size_t)blockIdx.x * 256 + threadIdx.x) << 3;
  const float4 v0 = *reinterpret_cast<const float4*>(X + i);
  const float4 v1 = *reinterpret_cast<const float4*>(X + i + 4);
  half8 h;
  h[0] = (_Float16)v0.x; h[1] = (_Float16)v0.y;
  h[2] = (_Float16)v0.z; h[3] = (_Float16)v0.w;
  h[4] = (_Float16)v1.x; h[5] = (_Float16)v1.y;
  h[6] = (_Float16)v1.z; h[7] = (_Float16)v1.w;
  *reinterpret_cast<half8*>(X16 + i) = h;
}

// ================= gemm1 core (r15 verbatim: BK=32, 3 buffers, vmcnt(4)) =================
#define STAGE_P1(buf)                                \
  do {                                               \
    gload16(pA0, &As[buf][t << 3]);                  \
    gload16(pA1, &As[buf][(256 + t) << 3]);          \
    gload16(pB0, &Bs[buf][t << 3]);                  \
    gload16(pB1, &Bs[buf][(256 + t) << 3]);          \
    pA0 += 32; pA1 += 32; pB0 += 32; pB1 += 32;      \
  } while (0)

#define FRAGS_MFMA1(buf)                                                            \
  do {                                                                              \
    half8 af[4], bf[4];                                                             \
    _Pragma("unroll") for (int f = 0; f < 4; ++f) {                                 \
      af[f] = *reinterpret_cast<const half8*>(                                      \
          &As[buf][(((wr << 6) + (f << 4) + lr) << 5) + (lg << 3)]);                \
      bf[f] = *reinterpret_cast<const half8*>(                                      \
          &Bs[buf][(((wc << 6) + (f << 4) + lr) << 5) + (lg << 3)]);                \
    }                                                                               \
    _Pragma("unroll") for (int fm = 0; fm < 4; ++fm)                                \
        _Pragma("unroll") for (int fn = 0; fn < 4; ++fn)                            \
        acc[fm][fn] = __builtin_amdgcn_mfma_f32_16x16x32_f16(af[fm], bf[fn],        \
                                                             acc[fm][fn], 0, 0, 0); \
  } while (0)

#define K_LOOP1()                                                                   \
  do {                                                                              \
    const int row_ = t >> 2;                                                        \
    const int c8_ = (t & 3) << 3;                                                   \
    const _Float16* pA0 =                                                           \
        Ap + ((size_t)(bm + row_) << 9) + (klo << 5) + c8_;                         \
    const _Float16* pA1 = pA0 + ((size_t)64 << 9);                                  \
    const _Float16* pB0 =                                                           \
        Bp + ((size_t)(bn + row_) << 9) + (klo << 5) + c8_;                         \
    const _Float16* pB1 = pB0 + ((size_t)64 << 9);                                  \
    STAGE_P1(0);                                                                    \
    STAGE_P1(1);                                                                    \
    int cb = 0;                                                                     \
    for (int kt = klo; kt <= khi; ++kt) {                                           \
      if (kt < khi) { WAITV4(); } else { WAITV0(); }                                \
      SCHEDB();                                                                     \
      BARRIER();                                                                    \
      SCHEDB();                                                                     \
      if (kt + 2 <= khi) {                                                          \
        const int sb = (cb + 2 >= 3) ? cb - 1 : cb + 2;                             \
        STAGE_P1(sb);                                                               \
      }                                                                             \
      FRAGS_MFMA1(cb);                                                              \
      cb = (cb == 2) ? 0 : cb + 1;                                                  \
    }                                                                               \
  } while (0)

// ---------------- stage 1: Ys^T = G_s * X^T (B = X rows) ----------------
// Grid (8, 288). r15 decode: blocks sharing an X row-panel co-locate per XCD.
__global__ __launch_bounds__(256) void gemm1_k(const _Float16* __restrict__ X16,
                                               const _Float16* __restrict__ G16,
                                               _Float16* __restrict__ T16) {
  __shared__ __align__(16) _Float16 As[3][128 * 32];
  __shared__ __align__(16) _Float16 Bs[3][128 * 32];
  const int t = threadIdx.x;
  const int lane = t & 63, wave = t >> 6;
  const int wr = wave >> 1, wc = wave & 1;
  const int lr = lane & 15, lg = lane >> 4;
  const int idx = blockIdx.x;             // 0..7
  const int idy = blockIdx.y;             // 0..287
  const int idx12 = idy % 12;             // bm + 4*s
  const int q = idx + ((idy / 12) << 3);  // 0..191 = bn + 4*slice
  const int bn = (q & 3) << 7;
  const int slice = q >> 2;
  const int bm = (idx12 & 3) << 7;
  const int s = idx12 >> 2;
  const int Rs[3] = {45, 240, 750};
  const int R = Rs[s];
  const _Float16* Ap = G16 + ((size_t)s << 18);      // A = G_s (bm rows, band clip)
  const _Float16* Bp = X16 + ((size_t)slice << 18);  // B = X rows
  _Float16* Tout = T16 + ((size_t)(s * NSL + slice) << 18);  // Tout[a][b] = Ys^T

  int klo = bm - R;
  klo = (klo > 0 ? klo : 0) >> 5;
  int khi = bm + 127 + R;
  if (khi > 511) khi = 511;
  khi >>= 5;

  f32x4 acc[4][4];
#pragma unroll
  for (int i = 0; i < 4; ++i)
#pragma unroll
    for (int j = 0; j < 4; ++j) acc[i][j] = (f32x4){0.f, 0.f, 0.f, 0.f};

  K_LOOP1();

  // D[a][b]: a = bm+wr*64+fm*16+lg*4+j, b = bn+wc*64+fn*16+lr. Row-major runs.
#pragma unroll
  for (int fm = 0; fm < 4; ++fm)
#pragma unroll
    for (int fn = 0; fn < 4; ++fn) {
      const int a0 = bm + (wr << 6) + (fm << 4) + (lg << 2);
      const int b0 = bn + (wc << 6) + (fn << 4) + lr;
#pragma unroll
      for (int j = 0; j < 4; ++j)
        Tout[((size_t)(a0 + j) << 9) + b0] = (_Float16)acc[fm][fn][j];
    }
}

// ================= gemm2 core (BK=64, 2 buffers, granule-XOR swizzle) =================
// LDS granule (row, g) holds global granule g ^ (row&7); reads apply the same
// XOR (involution; r12-verified). global_load_lds dest stays linear.
#define STAGE8SW(buf)                                  \
  do {                                                 \
    gload16(pA0, &As[buf][t << 3]);                    \
    gload16(pA1, &As[buf][(256 + t) << 3]);            \
    gload16(pA2, &As[buf][(512 + t) << 3]);            \
    gload16(pA3, &As[buf][(768 + t) << 3]);            \
    gload16(pB0, &Bs[buf][t << 3]);                    \
    gload16(pB1, &Bs[buf][(256 + t) << 3]);            \
    gload16(pB2, &Bs[buf][(512 + t) << 3]);            \
    gload16(pB3, &Bs[buf][(768 + t) << 3]);            \
    pA0 += 64; pA1 += 64; pA2 += 64; pA3 += 64;        \
    pB0 += 64; pB1 += 64; pB2 += 64; pB3 += 64;        \
  } while (0)

#define FRAGS_MFMA2(buf)                                                            \
  do {                                                                              \
    _Pragma("unroll") for (int ks = 0; ks < 2; ++ks) {                              \
      half8 af[4], bf[4];                                                           \
      _Pragma("unroll") for (int f = 0; f < 4; ++f) {                               \
        af[f] = *reinterpret_cast<const half8*>(                                    \
            &As[buf][(((wr << 6) + (f << 4) + lr) << 6) +                           \
                     ((((ks << 2) + lg) ^ (lr & 7)) << 3)]);                        \
        bf[f] = *reinterpret_cast<const half8*>(                                    \
            &Bs[buf][(((wc << 6) + (f << 4) + lr) << 6) +                           \
                     ((((ks << 2) + lg) ^ (lr & 7)) << 3)]);                        \
      }                                                                             \
      _Pragma("unroll") for (int fm = 0; fm < 4; ++fm)                              \
          _Pragma("unroll") for (int fn = 0; fn < 4; ++fn)                          \
          acc[fm][fn] = __builtin_amdgcn_mfma_f32_16x16x32_f16(af[fm], bf[fn],      \
                                                               acc[fm][fn], 0, 0, 0); \
    }                                                                               \
  } while (0)

// r16-proven loop: prologue stage buf0; per iter: __syncthreads (drains this
// wave's stage loads + all reads), stage other buf, compute current.
#define K_LOOP2()                                                                   \
  do {                                                                              \
    const int rA_ = t >> 3;                                                         \
    const int gsw_ = ((t & 7) ^ ((t >> 3) & 7)) << 3;  /* pre-swizzled source */    \
    const _Float16* pA0 = Ap + ((size_t)(bm + rA_) << 9) + (klo << 6) + gsw_;       \
    const _Float16* pA1 = pA0 + ((size_t)32 << 9);                                  \
    const _Float16* pA2 = pA0 + ((size_t)64 << 9);                                  \
    const _Float16* pA3 = pA0 + ((size_t)96 << 9);                                  \
    const _Float16* pB0 = Bp + ((size_t)(bn + rA_) << 9) + (klo << 6) + gsw_;       \
    const _Float16* pB1 = pB0 + ((size_t)32 << 9);                                  \
    const _Float16* pB2 = pB0 + ((size_t)64 << 9);                                  \
    const _Float16* pB3 = pB0 + ((size_t)96 << 9);                                  \
    STAGE8SW(0);                                                                    \
    int cb = 0;                                                                     \
    for (int kt = klo; kt <= khi; ++kt) {                                           \
      __syncthreads();                                                              \
      if (kt < khi) STAGE8SW(cb ^ 1);                                               \
      FRAGS_MFMA2(cb);                                                              \
      cb ^= 1;                                                                      \
    }                                                                               \
  } while (0)

// ---------------- stage 2 fused: out = sum_s log(G_s*Y_s + 1)/3, + min/max ----------------
// Grid (8, 96). r15 decode: 4 bm-blocks sharing T16 row-panels co-locate.
__global__ __launch_bounds__(256) void gemm2_k(const _Float16* __restrict__ G16,
                                               const _Float16* __restrict__ T16,
                                               float* __restrict__ out,
                                               unsigned* __restrict__ mm) {
  __shared__ __align__(16) _Float16 As[2][128 * 64];
  __shared__ __align__(16) _Float16 Bs[2][128 * 64];
  __shared__ float smn[4], smx[4];
  const int t = threadIdx.x;
  const int lane = t & 63, wave = t >> 6;
  const int wr = wave >> 1, wc = wave & 1;
  const int lr = lane & 15, lg = lane >> 4;
  const int idx = blockIdx.x;             // 0..7
  const int idy = blockIdx.y;             // 0..95
  const int bm = (idy & 3) << 7;
  const int q = idx + ((idy >> 2) << 3);  // 0..191 = bn + 4*slice
  const int bn = (q & 3) << 7;
  const int slice = q >> 2;
  const float w3 = 1.f / 3.f;
  const int Rs[3] = {45, 240, 750};

  f32x4 res[4][4];
#pragma unroll
  for (int i = 0; i < 4; ++i)
#pragma unroll
    for (int j = 0; j < 4; ++j) res[i][j] = (f32x4){0.f, 0.f, 0.f, 0.f};

#pragma unroll 1
  for (int s = 0; s < 3; ++s) {
    const int R = Rs[s];
    const _Float16* Ap = G16 + ((size_t)s << 18);
    const _Float16* Bp = T16 + ((size_t)(s * NSL + slice) << 18);
    int klo = bm - R;
    klo = (klo > 0 ? klo : 0) >> 6;
    int khi = bm + 127 + R;
    if (khi > 511) khi = 511;
    khi >>= 6;

    f32x4 acc[4][4];
#pragma unroll
    for (int i = 0; i < 4; ++i)
#pragma unroll
      for (int j = 0; j < 4; ++j) acc[i][j] = (f32x4){0.f, 0.f, 0.f, 0.f};

    __syncthreads();  // full drain: prev sigma's reads done before restaging buf0
    K_LOOP2();

#pragma unroll
    for (int fm = 0; fm < 4; ++fm)
#pragma unroll
      for (int fn = 0; fn < 4; ++fn)
#pragma unroll
        for (int j = 0; j < 4; ++j)
          res[fm][fn][j] += w3 * __logf(acc[fm][fn][j] + 1.f);
  }

  // write out + fused per-channel min/max
  float mn = 3.4e38f, mx = -3.4e38f;
#pragma unroll
  for (int fm = 0; fm < 4; ++fm)
#pragma unroll
    for (int fn = 0; fn < 4; ++fn) {
      const int rb = bm + (wr << 6) + (fm << 4) + (lg << 2);
      const int cg = bn + (wc << 6) + (fn << 4) + lr;
      float* op = out + ((size_t)slice << 18) + ((size_t)rb << 9) + cg;
#pragma unroll
      for (int j = 0; j < 4; ++j) {
        const float v = res[fm][fn][j];
        op[j << 9] = v;
        mn = fminf(mn, v);
        mx = fmaxf(mx, v);
      }
    }
#pragma unroll
  for (int off = 32; off > 0; off >>= 1) {
    mn = fminf(mn, __shfl_xor(mn, off));
    mx = fmaxf(mx, __shfl_xor(mx, off));
  }
  if (lane == 0) {
    smn[wave] = mn;
    smx[wave] = mx;
  }
  __syncthreads();
  if (t == 0) {
    mn = fminf(fminf(smn[0], smn[1]), fminf(smn[2], smn[3]));
    mx = fmaxf(fmaxf(smx[0], smx[1]), fmaxf(smx[2], smx[3]));
    const int ch = slice % 3;
    atomicMin(&mm[ch], __float_as_uint(mn));  // values >= 0
    atomicMax(&mm[3 + ch], __float_as_uint(mx));
  }
}

// ---------------- normalize ----------------
__global__ __launch_bounds__(256) void norm_k(float* __restrict__ r,
                                              const unsigned* __restrict__ mm) {
  const int b = blockIdx.x;
  const int slice = b >> 4;
  const int piece = b & 15;
  const int ch = slice % 3;
  const float mn = __uint_as_float(mm[ch]);
  const float mx = __uint_as_float(mm[3 + ch]);
  const float inv = 1.f / (mx - mn);
  float* p = r + ((size_t)slice << 18) + (piece << 14);
  const int t = threadIdx.x;
  for (int q = 0; q < 16; ++q) {
    float4 v = *reinterpret_cast<const float4*>(&p[(q * 256 + t) << 2]);
    v.x = (v.x - mn) * inv;
    v.y = (v.y - mn) * inv;
    v.z = (v.z - mn) * inv;
    v.w = (v.w - mn) * inv;
    *reinterpret_cast<float4*>(&p[(q * 256 + t) << 2]) = v;
  }
}

extern "C" void kernel_launch(void* const* d_in, const int* in_sizes, int n_in,
                              void* d_out, int out_size, void* d_ws, size_t ws_size,
                              hipStream_t stream) {
  const float* img = (const float*)d_in[0];
  float* out = (float*)d_out;
  float* wsf = (float*)d_ws;
  unsigned* mm = (unsigned*)(wsf + MM_OFF);
  _Float16* G16 = (_Float16*)((char*)d_ws + G16_BYTE_OFF);
  _Float16* X16 = (_Float16*)((char*)d_ws + X16_BYTE_OFF);
  _Float16* T16 = (_Float16*)((char*)d_ws + T16_BYTE_OFF);

  wkern<<<3, 256, 0, stream>>>(wsf);
  mm_init<<<1, 64, 0, stream>>>(mm);
  gkern<<<dim3(512, 3), 256, 0, stream>>>(wsf, G16);
  xconv<<<6144, 256, 0, stream>>>(img, X16);

  gemm1_k<<<dim3(8, 288), 256, 0, stream>>>(X16, G16, T16);
  gemm2_k<<<dim3(8, 96), 256, 0, stream>>>(G16, T16, out, mm);

  norm_k<<<768, 256, 0, stream>>>(out, mm);
}

// Round 18
// 144.738 us; speedup vs baseline: 1.1424x; 1.0201x over previous
//
#include <hip/hip_runtime.h>
#include <math.h>

// Retinex MSR via GEMM: blur_s = G_s * X * G_s  (G_s symmetric Toeplitz blur).
// xconv: X -> f16. gemm1: Ys^T[a][b] = sum_k G_s[a][k] X[b][k].
// gemm2: out = sum_s log(G_s*Y_s + 1)/3 + fused min/max.
// BOTH GEMMs now use the r17-verified core: BK=64, TWO LDS buffers, one
// __syncthreads per K-step, BOTH-SIDES granule XOR swizzle (bank-conflict 0),
// pointer staging, r15 XCD-aware block decode. norm: min-max stretch.

#define NSL 48

// d_ws layout:
#define W0_OFF 0      // sigma 15:  16 zero | 91 w | zeros   (alloc 512 floats)
#define W1_OFF 512    // sigma 80:  16 zero | 481 w | zeros  (alloc 768)
#define W2_OFF 1280   // sigma 250: 16 zero | 1501 w | zeros (alloc 1536)
#define MM_OFF 2816   // 6 uints: min[3], max[3]
#define G16_BYTE_OFF 16384     // 3 * 512*512 f16   (1.5 MiB)
#define X16_BYTE_OFF 1589248   // 48 * 512*512 f16  (24 MiB)
#define T16_BYTE_OFF 26755072  // 3 * 48 * 512*512 f16 (72 MiB)

typedef _Float16 half8 __attribute__((ext_vector_type(8)));
typedef float f32x4 __attribute__((ext_vector_type(4)));

__device__ __forceinline__ void gload16(const void* g, void* l) {
  __builtin_amdgcn_global_load_lds(
      (const __attribute__((address_space(1))) void*)g,
      (__attribute__((address_space(3))) void*)l, 16, 0, 0);
}

// ---------------- weights ----------------
__global__ void wkern(float* __restrict__ ws) {
  __shared__ float red[256];
  const int s = blockIdx.x;
  const int Ks[3] = {91, 481, 1501};
  const float sg[3] = {15.f, 80.f, 250.f};
  const int off[3] = {W0_OFF, W1_OFF, W2_OFF};
  const int alloc[3] = {512, 768, 1536};
  const int K = Ks[s], A = alloc[s];
  float* wb = ws + off[s];
  const int t = threadIdx.x;
  for (int i = t; i < A; i += 256) wb[i] = 0.f;
  __syncthreads();
  const float inv2s2 = 1.f / (2.f * sg[s] * sg[s]);
  float part = 0.f;
  for (int i = t; i < K; i += 256) {
    const float d = (float)(i - K / 2);
    const float e = __expf(-d * d * inv2s2);
    wb[16 + i] = e;
    part += e;
  }
  red[t] = part;
  __syncthreads();
  for (int st = 128; st > 0; st >>= 1) {
    if (t < st) red[t] += red[t + st];
    __syncthreads();
  }
  const float inv = 1.f / red[0];
  for (int i = t; i < K; i += 256) wb[16 + i] *= inv;
}

__global__ void mm_init(unsigned* __restrict__ mm) {
  const int t = threadIdx.x;
  if (t < 3) mm[t] = 0xFFFFFFFFu;
  else if (t < 6) mm[t] = 0u;
}

// ---------------- build G matrices (fp16) ----------------
__global__ void gkern(const float* __restrict__ ws, _Float16* __restrict__ gb) {
  const int y = blockIdx.x;
  const int s = blockIdx.y;
  const int Rs[3] = {45, 240, 750};
  const int off[3] = {W0_OFF, W1_OFF, W2_OFF};
  const float* w = ws + off[s] + 16;
  _Float16* g = gb + ((size_t)s << 18) + ((size_t)y << 9);
  const int R = Rs[s], K = 2 * R + 1;
  for (int x = threadIdx.x; x < 512; x += 256) {
    const int i = x - y + R;
    const float v = (i >= 0 && i < K) ? w[i] : 0.f;
    g[x] = (_Float16)v;
  }
}

// ---------------- X fp32 -> fp16 ----------------
__global__ __launch_bounds__(256) void xconv(const float* __restrict__ X,
                                             _Float16* __restrict__ X16) {
  const size_t i = ((size_t)blockIdx.x * 256 + threadIdx.x) << 3;
  const float4 v0 = *reinterpret_cast<const float4*>(X + i);
  const float4 v1 = *reinterpret_cast<const float4*>(X + i + 4);
  half8 h;
  h[0] = (_Float16)v0.x; h[1] = (_Float16)v0.y;
  h[2] = (_Float16)v0.z; h[3] = (_Float16)v0.w;
  h[4] = (_Float16)v1.x; h[5] = (_Float16)v1.y;
  h[6] = (_Float16)v1.z; h[7] = (_Float16)v1.w;
  *reinterpret_cast<half8*>(X16 + i) = h;
}

// ======== shared GEMM core (r17-verified): BK=64, 2 buffers, granule-XOR ========
// LDS granule (row, g) holds global granule g ^ (row&7); reads apply the same
// XOR (involution). global_load_lds dest stays linear per wave.
#define STAGE8SW(buf)                                  \
  do {                                                 \
    gload16(pA0, &As[buf][t << 3]);                    \
    gload16(pA1, &As[buf][(256 + t) << 3]);            \
    gload16(pA2, &As[buf][(512 + t) << 3]);            \
    gload16(pA3, &As[buf][(768 + t) << 3]);            \
    gload16(pB0, &Bs[buf][t << 3]);                    \
    gload16(pB1, &Bs[buf][(256 + t) << 3]);            \
    gload16(pB2, &Bs[buf][(512 + t) << 3]);            \
    gload16(pB3, &Bs[buf][(768 + t) << 3]);            \
    pA0 += 64; pA1 += 64; pA2 += 64; pA3 += 64;        \
    pB0 += 64; pB1 += 64; pB2 += 64; pB3 += 64;        \
  } while (0)

#define FRAGS_MFMA(buf)                                                             \
  do {                                                                              \
    _Pragma("unroll") for (int ks = 0; ks < 2; ++ks) {                              \
      half8 af[4], bf[4];                                                           \
      _Pragma("unroll") for (int f = 0; f < 4; ++f) {                               \
        af[f] = *reinterpret_cast<const half8*>(                                    \
            &As[buf][(((wr << 6) + (f << 4) + lr) << 6) +                           \
                     ((((ks << 2) + lg) ^ (lr & 7)) << 3)]);                        \
        bf[f] = *reinterpret_cast<const half8*>(                                    \
            &Bs[buf][(((wc << 6) + (f << 4) + lr) << 6) +                           \
                     ((((ks << 2) + lg) ^ (lr & 7)) << 3)]);                        \
      }                                                                             \
      _Pragma("unroll") for (int fm = 0; fm < 4; ++fm)                              \
          _Pragma("unroll") for (int fn = 0; fn < 4; ++fn)                          \
          acc[fm][fn] = __builtin_amdgcn_mfma_f32_16x16x32_f16(af[fm], bf[fn],      \
                                                               acc[fm][fn], 0, 0, 0); \
    }                                                                               \
  } while (0)

// r16/r17-proven loop: prologue stage buf0; per iter: __syncthreads (drains
// this wave's stage loads + all LDS reads), stage other buf, compute current.
#define K_LOOP()                                                                    \
  do {                                                                              \
    const int rA_ = t >> 3;                                                         \
    const int gsw_ = ((t & 7) ^ ((t >> 3) & 7)) << 3; /* pre-swizzled source */     \
    const _Float16* pA0 = Ap + ((size_t)(bm + rA_) << 9) + (klo << 6) + gsw_;       \
    const _Float16* pA1 = pA0 + ((size_t)32 << 9);                                  \
    const _Float16* pA2 = pA0 + ((size_t)64 << 9);                                  \
    const _Float16* pA3 = pA0 + ((size_t)96 << 9);                                  \
    const _Float16* pB0 = Bp + ((size_t)(bn + rA_) << 9) + (klo << 6) + gsw_;       \
    const _Float16* pB1 = pB0 + ((size_t)32 << 9);                                  \
    const _Float16* pB2 = pB0 + ((size_t)64 << 9);                                  \
    const _Float16* pB3 = pB0 + ((size_t)96 << 9);                                  \
    STAGE8SW(0);                                                                    \
    int cb = 0;                                                                     \
    for (int kt = klo; kt <= khi; ++kt) {                                           \
      __syncthreads();                                                              \
      if (kt < khi) STAGE8SW(cb ^ 1);                                               \
      FRAGS_MFMA(cb);                                                               \
      cb ^= 1;                                                                      \
    }                                                                               \
  } while (0)

// ---------------- stage 1: Ys^T = G_s * X^T (B = X rows) ----------------
// Grid (8, 288). r15 decode: the 12 blocks sharing an X row-panel (same
// bn,slice; bm x s varying) have identical linear%8 -> same XCD.
__global__ __launch_bounds__(256) void gemm1_k(const _Float16* __restrict__ X16,
                                               const _Float16* __restrict__ G16,
                                               _Float16* __restrict__ T16) {
  __shared__ __align__(16) _Float16 As[2][128 * 64];
  __shared__ __align__(16) _Float16 Bs[2][128 * 64];
  const int t = threadIdx.x;
  const int lane = t & 63, wave = t >> 6;
  const int wr = wave >> 1, wc = wave & 1;
  const int lr = lane & 15, lg = lane >> 4;
  const int idx = blockIdx.x;             // 0..7
  const int idy = blockIdx.y;             // 0..287
  const int idx12 = idy % 12;             // bm + 4*s
  const int q = idx + ((idy / 12) << 3);  // 0..191 = bn + 4*slice
  const int bn = (q & 3) << 7;
  const int slice = q >> 2;
  const int bm = (idx12 & 3) << 7;
  const int s = idx12 >> 2;
  const int Rs[3] = {45, 240, 750};
  const int R = Rs[s];
  const _Float16* Ap = G16 + ((size_t)s << 18);      // A = G_s (bm rows, band clip)
  const _Float16* Bp = X16 + ((size_t)slice << 18);  // B = X rows
  _Float16* Tout = T16 + ((size_t)(s * NSL + slice) << 18);  // Tout[a][b] = Ys^T

  int klo = bm - R;
  klo = (klo > 0 ? klo : 0) >> 6;
  int khi = bm + 127 + R;
  if (khi > 511) khi = 511;
  khi >>= 6;

  f32x4 acc[4][4];
#pragma unroll
  for (int i = 0; i < 4; ++i)
#pragma unroll
    for (int j = 0; j < 4; ++j) acc[i][j] = (f32x4){0.f, 0.f, 0.f, 0.f};

  K_LOOP();

  // D[a][b]: a = bm+wr*64+fm*16+lg*4+j, b = bn+wc*64+fn*16+lr. Row-major runs.
#pragma unroll
  for (int fm = 0; fm < 4; ++fm)
#pragma unroll
    for (int fn = 0; fn < 4; ++fn) {
      const int a0 = bm + (wr << 6) + (fm << 4) + (lg << 2);
      const int b0 = bn + (wc << 6) + (fn << 4) + lr;
#pragma unroll
      for (int j = 0; j < 4; ++j)
        Tout[((size_t)(a0 + j) << 9) + b0] = (_Float16)acc[fm][fn][j];
    }
}

// ---------------- stage 2 fused: out = sum_s log(G_s*Y_s + 1)/3, + min/max ----------------
// Grid (8, 96). r15 decode: 4 bm-blocks sharing T16 row-panels co-locate.
__global__ __launch_bounds__(256) void gemm2_k(const _Float16* __restrict__ G16,
                                               const _Float16* __restrict__ T16,
                                               float* __restrict__ out,
                                               unsigned* __restrict__ mm) {
  __shared__ __align__(16) _Float16 As[2][128 * 64];
  __shared__ __align__(16) _Float16 Bs[2][128 * 64];
  __shared__ float smn[4], smx[4];
  const int t = threadIdx.x;
  const int lane = t & 63, wave = t >> 6;
  const int wr = wave >> 1, wc = wave & 1;
  const int lr = lane & 15, lg = lane >> 4;
  const int idx = blockIdx.x;             // 0..7
  const int idy = blockIdx.y;             // 0..95
  const int bm = (idy & 3) << 7;
  const int q = idx + ((idy >> 2) << 3);  // 0..191 = bn + 4*slice
  const int bn = (q & 3) << 7;
  const int slice = q >> 2;
  const float w3 = 1.f / 3.f;
  const int Rs[3] = {45, 240, 750};

  f32x4 res[4][4];
#pragma unroll
  for (int i = 0; i < 4; ++i)
#pragma unroll
    for (int j = 0; j < 4; ++j) res[i][j] = (f32x4){0.f, 0.f, 0.f, 0.f};

#pragma unroll 1
  for (int s = 0; s < 3; ++s) {
    const int R = Rs[s];
    const _Float16* Ap = G16 + ((size_t)s << 18);
    const _Float16* Bp = T16 + ((size_t)(s * NSL + slice) << 18);
    int klo = bm - R;
    klo = (klo > 0 ? klo : 0) >> 6;
    int khi = bm + 127 + R;
    if (khi > 511) khi = 511;
    khi >>= 6;

    f32x4 acc[4][4];
#pragma unroll
    for (int i = 0; i < 4; ++i)
#pragma unroll
      for (int j = 0; j < 4; ++j) acc[i][j] = (f32x4){0.f, 0.f, 0.f, 0.f};

    __syncthreads();  // full drain: prev sigma's reads done before restaging buf0
    K_LOOP();

#pragma unroll
    for (int fm = 0; fm < 4; ++fm)
#pragma unroll
      for (int fn = 0; fn < 4; ++fn)
#pragma unroll
        for (int j = 0; j < 4; ++j)
          res[fm][fn][j] += w3 * __logf(acc[fm][fn][j] + 1.f);
  }

  // write out + fused per-channel min/max
  float mn = 3.4e38f, mx = -3.4e38f;
#pragma unroll
  for (int fm = 0; fm < 4; ++fm)
#pragma unroll
    for (int fn = 0; fn < 4; ++fn) {
      const int rb = bm + (wr << 6) + (fm << 4) + (lg << 2);
      const int cg = bn + (wc << 6) + (fn << 4) + lr;
      float* op = out + ((size_t)slice << 18) + ((size_t)rb << 9) + cg;
#pragma unroll
      for (int j = 0; j < 4; ++j) {
        const float v = res[fm][fn][j];
        op[j << 9] = v;
        mn = fminf(mn, v);
        mx = fmaxf(mx, v);
      }
    }
#pragma unroll
  for (int off = 32; off > 0; off >>= 1) {
    mn = fminf(mn, __shfl_xor(mn, off));
    mx = fmaxf(mx, __shfl_xor(mx, off));
  }
  if (lane == 0) {
    smn[wave] = mn;
    smx[wave] = mx;
  }
  __syncthreads();
  if (t == 0) {
    mn = fminf(fminf(smn[0], smn[1]), fminf(smn[2], smn[3]));
    mx = fmaxf(fmaxf(smx[0], smx[1]), fmaxf(smx[2], smx[3]));
    const int ch = slice % 3;
    atomicMin(&mm[ch], __float_as_uint(mn));  // values >= 0
    atomicMax(&mm[3 + ch], __float_as_uint(mx));
  }
}

// ---------------- normalize ----------------
__global__ __launch_bounds__(256) void norm_k(float* __restrict__ r,
                                              const unsigned* __restrict__ mm) {
  const int b = blockIdx.x;
  const int slice = b >> 4;
  const int piece = b & 15;
  const int ch = slice % 3;
  const float mn = __uint_as_float(mm[ch]);
  const float mx = __uint_as_float(mm[3 + ch]);
  const float inv = 1.f / (mx - mn);
  float* p = r + ((size_t)slice << 18) + (piece << 14);
  const int t = threadIdx.x;
  for (int q = 0; q < 16; ++q) {
    float4 v = *reinterpret_cast<const float4*>(&p[(q * 256 + t) << 2]);
    v.x = (v.x - mn) * inv;
    v.y = (v.y - mn) * inv;
    v.z = (v.z - mn) * inv;
    v.w = (v.w - mn) * inv;
    *reinterpret_cast<float4*>(&p[(q * 256 + t) << 2]) = v;
  }
}

extern "C" void kernel_launch(void* const* d_in, const int* in_sizes, int n_in,
                              void* d_out, int out_size, void* d_ws, size_t ws_size,
                              hipStream_t stream) {
  const float* img = (const float*)d_in[0];
  float* out = (float*)d_out;
  float* wsf = (float*)d_ws;
  unsigned* mm = (unsigned*)(wsf + MM_OFF);
  _Float16* G16 = (_Float16*)((char*)d_ws + G16_BYTE_OFF);
  _Float16* X16 = (_Float16*)((char*)d_ws + X16_BYTE_OFF);
  _Float16* T16 = (_Float16*)((char*)d_ws + T16_BYTE_OFF);

  wkern<<<3, 256, 0, stream>>>(wsf);
  mm_init<<<1, 64, 0, stream>>>(mm);
  gkern<<<dim3(512, 3), 256, 0, stream>>>(wsf, G16);
  xconv<<<6144, 256, 0, stream>>>(img, X16);

  gemm1_k<<<dim3(8, 288), 256, 0, stream>>>(X16, G16, T16);
  gemm2_k<<<dim3(8, 96), 256, 0, stream>>>(G16, T16, out, mm);

  norm_k<<<768, 256, 0, stream>>>(out, mm);
}